// Round 2
// baseline (361.042 us; speedup 1.0000x reference)
//
#include <hip/hip_runtime.h>

#define NN 50000
#define NE 1600000
#define EP (NE + NN)   // edges + self loops
#define IN_DIM 256
#define HIDD 64
#define NCLS 10
#define NBKT 196                       // destination buckets: d >> 8
#define EPB 8192                       // edges per partition block
#define NPB ((EP + EPB - 1) / EPB)     // 202 partition blocks
#define BCAP 12288                     // fixed bucket capacity (exp 8418 +- 92)

typedef unsigned short u16;
typedef short bf16x8 __attribute__((ext_vector_type(8)));
typedef float f32x4 __attribute__((ext_vector_type(4)));
typedef unsigned u32x4 __attribute__((ext_vector_type(4)));

__device__ __forceinline__ float b2f(u16 v) { return __uint_as_float(((unsigned)v) << 16); }
__device__ __forceinline__ u16 f2b(float f) {
    unsigned u = __float_as_uint(f);
    unsigned r = (u + 0x7FFFu + ((u >> 16) & 1u)) >> 16;
    return (u16)r;
}

__device__ __forceinline__ void load_edge(const int* __restrict__ ei, int m, int g,
                                          int& s, int& d) {
    if (g < NE) {
        if (m) { s = ei[2 * (size_t)g]; d = ei[2 * ((size_t)NE + g)]; }
        else   { s = ei[g];             d = ei[NE + g]; }
    } else {
        s = d = g - NE;  // self loop
    }
    s = s < 0 ? 0 : (s >= NN ? NN - 1 : s);
    d = d < 0 ? 0 : (d >= NN ? NN - 1 : d);
}

// ---- weight transpose + augmented score rows (device helper) ----
__device__ __forceinline__ void wcvt_att_job(
    const float* __restrict__ W, const float* __restrict__ as,
    const float* __restrict__ ad, int K, int N, int H, u16* __restrict__ Wt,
    int idx) {
    if (idx >= K * (N + 16)) return;
    int n = idx / K, k = idx - n * K;
    if (n < N) { Wt[idx] = f2b(W[(size_t)k * N + n]); return; }
    int j = n - N;
    if (j >= 2 * H) { Wt[idx] = 0; return; }
    const float* att = (j & 1) ? ad : as;
    int h = j >> 1, C = N / H;
    float sum = 0.f;
    for (int c = 0; c < C; ++c)
        sum += W[(size_t)k * N + h * C + c] * att[h * C + c];
    Wt[idx] = f2b(sum);
}

// ---- single-pass partition into fixed-capacity bucket slots ----
__global__ __launch_bounds__(1024) void partition_k(
    const int* __restrict__ ei, int* __restrict__ gcursor,
    unsigned* __restrict__ bbuf,
    const float* __restrict__ W1, const float* __restrict__ as1,
    const float* __restrict__ ad1, u16* __restrict__ w1t,
    const float* __restrict__ W2, const float* __restrict__ as2,
    const float* __restrict__ ad2, u16* __restrict__ w2t) {
    __shared__ int hist[NBKT], base[NBKT], cur[NBKT];
    __shared__ unsigned stash[EPB];
    __shared__ int smode;
    int t = threadIdx.x, b = blockIdx.x;
    // side jobs: W1 on blocks 0..35 (36*1024 = 256*144), W2 on 36..45 (10*1024)
    if (b < 36) wcvt_att_job(W1, as1, ad1, 256, 128, 2, w1t, b * 1024 + t);
    else if (b < 46) wcvt_att_job(W2, as2, ad2, 128, 64, 1, w2t, (b - 36) * 1024 + t);
    // local dtype detect (wave 0)
    if (t < 64) {
        int nz = 0;
#pragma unroll
        for (int k = 0; k < 4; ++k)
            if (ei[2 * (t * 4 + k) + 1] != 0) nz = 1;
        unsigned long long bal = __ballot(nz);
        if (t == 0) smode = (bal == 0ULL) ? 1 : 0;  // 1 = int64 layout
    }
    for (int i = t; i < NBKT; i += 1024) hist[i] = 0;
    __syncthreads();
    int m = smode;
    int g0 = b * EPB;
    int gend = min(g0 + EPB, EP);
    for (int g = g0 + t; g < gend; g += 1024) {
        int s, d;
        load_edge(ei, m, g, s, d);
        stash[g - g0] = ((unsigned)s << 16) | (unsigned)d;
        atomicAdd(&hist[d >> 8], 1);
    }
    __syncthreads();
    for (int i = t; i < NBKT; i += 1024) {
        base[i] = hist[i] ? atomicAdd(&gcursor[i], hist[i]) : 0;
        cur[i] = 0;
    }
    __syncthreads();
    int cnt = gend - g0;
    for (int l = t; l < cnt; l += 1024) {
        unsigned p = stash[l];
        int d = p & 0xFFFF;
        int bb = d >> 8;
        int r = base[bb] + atomicAdd(&cur[bb], 1);
        if (r < BCAP)  // harden: adversarial skew can't write OOB
            bbuf[(size_t)bb * BCAP + r] = ((p >> 16) << 8) | (unsigned)(d & 255);
    }
}

// ---- per-bucket fine CSR (bucket-base scan fused in); 1024 threads/block ----
__global__ __launch_bounds__(1024) void bucket_csr_k(const unsigned* __restrict__ bbuf,
                                                     const int* __restrict__ gcursor,
                                                     int* __restrict__ row_ptr,
                                                     u16* __restrict__ csr_src) {
    __shared__ int bsc[256];
    __shared__ int hist[256], scn[256], cur[256];
    __shared__ int se0, scnt, stot;
    int b = blockIdx.x, t = threadIdx.x;
    int v = 0;
    if (t < 256) {
        v = (t < NBKT) ? min(gcursor[t], BCAP) : 0;
        bsc[t] = v;
        hist[t] = 0;
    }
    __syncthreads();
    for (int off = 1; off < 256; off <<= 1) {
        int x = (t < 256 && t >= off) ? bsc[t - off] : 0;
        __syncthreads();
        if (t < 256) bsc[t] += x;
        __syncthreads();
    }
    if (t == b) { se0 = bsc[t] - v; scnt = v; }
    if (t == NBKT - 1) stot = bsc[t];
    __syncthreads();
    int e0 = se0, cnt = scnt;
    const unsigned* bb = bbuf + (size_t)b * BCAP;
    for (int e = t; e < cnt; e += 1024)
        atomicAdd(&hist[bb[e] & 255], 1);
    __syncthreads();
    int hv = 0;
    if (t < 256) { hv = hist[t]; scn[t] = hv; }
    __syncthreads();
    for (int off = 1; off < 256; off <<= 1) {
        int x = (t < 256 && t >= off) ? scn[t - off] : 0;
        __syncthreads();
        if (t < 256) scn[t] += x;
        __syncthreads();
    }
    if (t < 256) {
        int ex = scn[t] - hv;  // exclusive within bucket
        int n = b * 256 + t;
        if (n < NN) row_ptr[n] = e0 + ex;
        cur[t] = e0 + ex;
    }
    __syncthreads();
    for (int e = t; e < cnt; e += 1024) {
        unsigned p = bb[e];
        int pos = atomicAdd(&cur[p & 255], 1);
        csr_src[pos] = (u16)(p >> 8);
    }
    if (b == 0 && t == 0) row_ptr[NN] = stot;
}

// ---- MFMA GEMM + fused scores ----
template <int K, int NF, int H, bool F32A>
__global__ __launch_bounds__(256) void gemm_mfma_att_k(
    const float* __restrict__ Af, const u16* __restrict__ Ab,
    const u16* __restrict__ Wt, u16* __restrict__ C,
    float* __restrict__ a_s, float* __restrict__ a_d) {
    constexpr int NTF = NF / 16, NT = NTF + 1, KS = K / 32;
    const int wave = threadIdx.x >> 6, lane = threadIdx.x & 63;
    const int quad = lane >> 4, l15 = lane & 15;
    const int m0 = blockIdx.x * 64 + wave * 16;
    int rowA = m0 + l15;
    if (rowA >= NN) rowA = NN - 1;
    const float* afp = F32A ? (Af + (size_t)rowA * K + quad * 8) : nullptr;
    const u16*   abp = F32A ? nullptr : (Ab + (size_t)rowA * K + quad * 8);
    const u16* bptr = Wt + (size_t)l15 * K + quad * 8;
    f32x4 acc[NT] = {};
#pragma unroll
    for (int ks = 0; ks < KS; ++ks) {
        bf16x8 af;
        if (F32A) {
            float4 v0 = *(const float4*)(afp + ks * 32);
            float4 v1 = *(const float4*)(afp + ks * 32 + 4);
            af[0] = (short)f2b(v0.x); af[1] = (short)f2b(v0.y);
            af[2] = (short)f2b(v0.z); af[3] = (short)f2b(v0.w);
            af[4] = (short)f2b(v1.x); af[5] = (short)f2b(v1.y);
            af[6] = (short)f2b(v1.z); af[7] = (short)f2b(v1.w);
        } else {
            af = *(const bf16x8*)(abp + ks * 32);
        }
        bf16x8 bf[NT];
#pragma unroll
        for (int nt = 0; nt < NT; ++nt)
            bf[nt] = *(const bf16x8*)(bptr + (size_t)nt * 16 * K + ks * 32);
#pragma unroll
        for (int nt = 0; nt < NT; ++nt)
            acc[nt] = __builtin_amdgcn_mfma_f32_16x16x32_bf16(af, bf[nt], acc[nt], 0, 0, 0);
    }
#pragma unroll
    for (int nt = 0; nt < NTF; ++nt) {
#pragma unroll
        for (int reg = 0; reg < 4; ++reg) {
            int row = m0 + quad * 4 + reg;
            if (row < NN) C[(size_t)row * NF + nt * 16 + l15] = f2b(acc[nt][reg]);
        }
    }
    if (l15 < 2 * H) {
        int h = l15 >> 1;
        float* dst = (l15 & 1) ? a_d : a_s;
#pragma unroll
        for (int reg = 0; reg < 4; ++reg) {
            int row = m0 + quad * 4 + reg;
            if (row < NN) dst[row * H + h] = acc[NTF][reg];
        }
    }
}

// ---- fused gather (bf16 h): one WAVE per node ----
// Round 2 insight: rounds 0/1 were pinned at 66.4us with identical L2
// line-request counts (3/edge layer1: 2 h-row + 1 a_s) despite 4x VMEM-
// instruction and 2x VALU changes -> the gather is L2 REQUEST-RATE bound.
// This version removes the per-edge a_s[src] gather: a_s is recomputed
// in-register from the gathered h row (a_s = sum_c h[c]*att_src[c]); the
// 16(8) lanes of a row-group hold the full row, so the dot is 8 FMA +
// 3 shfl_xor. Lanes q<LPR/2 hold head-0 channels, so each lane's exp()
// already matches the head its channels need -> no broadcast of ex at all.
// Line requests/edge: layer1 3 -> 2, layer2 2 -> 1.
template <int CH, int H, bool HEAD>
__global__ __launch_bounds__(256) void gat_gather_k(
    const int* __restrict__ row_ptr, const u16* __restrict__ csr_src,
    const float* __restrict__ att_s, const float* __restrict__ a_d,
    const u16* __restrict__ h, const float* __restrict__ bias,
    u16* __restrict__ outg, const float* __restrict__ Wl,
    const float* __restrict__ bl, float* __restrict__ outh) {
    constexpr int LPR = CH / 8;               // lanes per row (16B each): 16 or 8
    constexpr int G = 64 / LPR;               // rows (edges) per load round: 4 or 8
    constexpr int SH = (CH == 128) ? 8 : 7;   // log2(row bytes)
    int n = (blockIdx.x * blockDim.x + threadIdx.x) >> 6;  // global wave id = node
    int lane = threadIdx.x & 63;
    if (n >= NN) return;  // wave-uniform exit
    int r0 = row_ptr[n], r1 = row_ptr[n + 1];
    const int q = lane & (LPR - 1);           // position within row
    const int g = lane >> ((CH == 128) ? 4 : 3);  // row group
    const unsigned qoff = (unsigned)q * 16u;
    const unsigned char* h8 = (const unsigned char*)h;

    // per-lane att_src slice: channel (q*8+k). For H=2 the concat channel
    // index equals the flat [2][64] att index, so att_s[q*8+k] works for both.
    float4 av0 = *(const float4*)(att_s + q * 8);
    float4 av1 = *(const float4*)(att_s + q * 8 + 4);
    float attv[8] = {av0.x, av0.y, av0.z, av0.w, av1.x, av1.y, av1.z, av1.w};

    // destination score for my head (lanes q<LPR/2 hold head 0 channels)
    float adn = (H == 2) ? a_d[n * 2 + (q >> 3)] : a_d[n];

    float dh = 0.f;
    float acc[8];
#pragma unroll
    for (int v = 0; v < 8; ++v) acc[v] = 0.f;

    for (int base = r0; base < r1; base += 64) {
        int cnt = min(64, r1 - base);
        int idx = base + lane;
        bool act = idx < r1;
        // bit16 = validity; invalid lanes point at row 0 with ex forced to 0
        int slv = act ? ((int)csr_src[idx] | 0x10000) : 0;
        for (int j0 = 0; j0 < cnt; j0 += 4 * G) {
            int sr[4];
#pragma unroll
            for (int i = 0; i < 4; ++i)
                sr[i] = __builtin_amdgcn_ds_bpermute((j0 + i * G + g) << 2, slv);
            u32x4 hv[4];
#pragma unroll
            for (int i = 0; i < 4; ++i)
                hv[i] = *(const u32x4*)(
                    h8 + (((unsigned)(sr[i] & 0xFFFF) << SH) + qoff));
#pragma unroll
            for (int i = 0; i < 4; ++i) {
                float f[8];
#pragma unroll
                for (int k = 0; k < 4; ++k) {
                    unsigned w = hv[i][k];
                    f[2 * k]     = __uint_as_float(w << 16);
                    f[2 * k + 1] = __uint_as_float(w & 0xFFFF0000u);
                }
                // in-register a_s: dot of my 8 channels, reduce over the
                // 8 lanes of my head-half of the row
                float d = f[0] * attv[0];
#pragma unroll
                for (int k = 1; k < 8; ++k) d += f[k] * attv[k];
                d += __shfl_xor(d, 1);
                d += __shfl_xor(d, 2);
                d += __shfl_xor(d, 4);
                float e = d + adn;
                e = e > 0.f ? e : 0.2f * e;
                e = fminf(e, 60.f);
                float ex = __expf(e);
                ex = (sr[i] & 0x10000) ? ex : 0.f;
                dh += ex;
#pragma unroll
                for (int k = 0; k < 8; ++k) acc[k] += ex * f[k];
            }
        }
    }

    // dh: lanes within a group hold identical copies; reduce ACROSS groups
    // only (offsets LPR..32). For H=2 each lane ends with its own head's
    // denominator; for H=1 all lanes end with the full sum.
#pragma unroll
    for (int off = LPR; off < 64; off <<= 1) dh += __shfl_xor(dh, off);
    // partials across row groups (lanes with same q)
#pragma unroll
    for (int v = 0; v < 8; ++v) {
#pragma unroll
        for (int off = LPR; off < 64; off <<= 1)
            acc[v] += __shfl_xor(acc[v], off);
    }

    if (HEAD) {
        // redistribute so lane l holds channel l: select acc[l>>3] (cndmask
        // tree over bits 3..5), then bpermute from lane ((l&7)<<3)|(l>>3).
        float t01 = (lane & 8) ? acc[1] : acc[0];
        float t23 = (lane & 8) ? acc[3] : acc[2];
        float t45 = (lane & 8) ? acc[5] : acc[4];
        float t67 = (lane & 8) ? acc[7] : acc[6];
        float ta = (lane & 16) ? t23 : t01;
        float tb = (lane & 16) ? t67 : t45;
        float ts = (lane & 32) ? tb : ta;
        int srcl = ((lane & 7) << 3) | (lane >> 3);
        float vsw = __uint_as_float(
            __builtin_amdgcn_ds_bpermute(srcl << 2, __float_as_int(ts)));
        float v0 = vsw / dh + bias[lane];
        v0 = v0 > 0.f ? v0 : expm1f(v0);
#pragma unroll
        for (int cls = 0; cls < NCLS; ++cls) {
            float p = v0 * Wl[lane * NCLS + cls];
#pragma unroll
            for (int off = 32; off; off >>= 1) p += __shfl_xor(p, off);
            if (lane == cls) outh[(size_t)n * NCLS + cls] = p + bl[cls];
        }
    } else {
        if (g == 0) {  // groups are redundant after reduce; group 0 stores
            float vv[8];
#pragma unroll
            for (int k = 0; k < 8; ++k) {
                float t = acc[k] / dh + bias[q * 8 + k];
                vv[k] = t > 0.f ? t : expm1f(t);
            }
            u32x4 ov;
#pragma unroll
            for (int d = 0; d < 4; ++d)
                ov[d] = (unsigned)f2b(vv[2 * d]) |
                        ((unsigned)f2b(vv[2 * d + 1]) << 16);
            *(u32x4*)(outg + (size_t)n * CH + q * 8) = ov;
        }
    }
}

extern "C" void kernel_launch(void* const* d_in, const int* in_sizes, int n_in,
                              void* d_out, int out_size, void* d_ws, size_t ws_size,
                              hipStream_t stream) {
    const float* x   = (const float*)d_in[0];
    const int*   ei  = (const int*)d_in[1];
    const float* W1  = (const float*)d_in[2];
    const float* as1 = (const float*)d_in[3];
    const float* ad1 = (const float*)d_in[4];
    const float* b1  = (const float*)d_in[5];
    const float* W2  = (const float*)d_in[6];
    const float* as2 = (const float*)d_in[7];
    const float* ad2 = (const float*)d_in[8];
    const float* b2  = (const float*)d_in[9];
    const float* Wl  = (const float*)d_in[10];
    const float* bl  = (const float*)d_in[11];
    float* out = (float*)d_out;

    // ---- workspace layout: ~31 MB (bbuf overlays g1: 9.63 MB <= 12.8 MB) ----
    float* ws = (float*)d_ws;
    size_t o = 0;
    u16* hb  = (u16*)(ws + o); o += (size_t)NN * 64;    // bf16 h1[NN][128] / h2[NN][64]
    u16* g1  = (u16*)(ws + o); o += (size_t)NN * 64;    // bf16 g1 [NN][128]  (= bbuf space)
    unsigned* bbuf = (unsigned*)g1;
    u16* w1t = (u16*)(ws + o); o += 144 * 256 / 2;      // bf16 W1^T+att [144][256]
    u16* w2t = (u16*)(ws + o); o += 80 * 128 / 2;       // bf16 W2^T+att [80][128]
    float* a_s = ws + o;       o += (size_t)NN * 2;
    float* a_d = ws + o;       o += (size_t)NN * 2;
    int* ints = (int*)(ws + o);
    size_t io = 0;
    int* gcursor  = ints + io; io += NBKT;
    int* row_ptr  = ints + io; io += NN + 1;
    u16* csr_src  = (u16*)(ints + io); io += (EP + 1) / 2;

    // ---- CSR build: memset + single edge pass (with setup side jobs) + bucket pass
    hipMemsetAsync(gcursor, 0, NBKT * sizeof(int), stream);
    partition_k<<<NPB, 1024, 0, stream>>>(ei, gcursor, bbuf,
                                          W1, as1, ad1, w1t, W2, as2, ad2, w2t);
    bucket_csr_k<<<NBKT, 1024, 0, stream>>>(bbuf, gcursor, row_ptr, csr_src);

    const int gatherBlocks = (NN + 3) / 4;  // 4 waves (nodes) per 256-thread block
    const int gemmBlocks = (NN + 63) / 64;

    // ---- layer 1: GATConv(256 -> 64, heads=2, concat) + ELU ----
    gemm_mfma_att_k<256, 128, 2, true><<<gemmBlocks, 256, 0, stream>>>(
        x, nullptr, w1t, hb, a_s, a_d);
    gat_gather_k<128, 2, false><<<gatherBlocks, 256, 0, stream>>>(
        row_ptr, csr_src, as1, a_d, hb, b1, g1, nullptr, nullptr, nullptr);

    // ---- layer 2: GATConv(128 -> 64, heads=1) + ELU + fused head ----
    gemm_mfma_att_k<128, 64, 1, false><<<gemmBlocks, 256, 0, stream>>>(
        nullptr, g1, w2t, hb, a_s, a_d);
    gat_gather_k<64, 1, true><<<gatherBlocks, 256, 0, stream>>>(
        row_ptr, csr_src, as2, a_d, hb, b2, nullptr, Wl, bl, out);
}

// Round 4
// 349.970 us; speedup vs baseline: 1.0316x; 1.0316x over previous
//
#include <hip/hip_runtime.h>

#define NN 50000
#define NE 1600000
#define EP (NE + NN)   // edges + self loops
#define IN_DIM 256
#define HIDD 64
#define NCLS 10
#define NBKT 196                       // destination buckets: d >> 8
#define EPB 8192                       // edges per partition block
#define NPB ((EP + EPB - 1) / EPB)     // 202 partition blocks
#define BCAP 12288                     // fixed bucket capacity (exp 8418 +- 92)

typedef unsigned short u16;
typedef short bf16x8 __attribute__((ext_vector_type(8)));
typedef float f32x4 __attribute__((ext_vector_type(4)));

__device__ __forceinline__ float b2f(u16 v) { return __uint_as_float(((unsigned)v) << 16); }
__device__ __forceinline__ u16 f2b(float f) {
    unsigned u = __float_as_uint(f);
    unsigned r = (u + 0x7FFFu + ((u >> 16) & 1u)) >> 16;
    return (u16)r;
}

__device__ __forceinline__ void load_edge(const int* __restrict__ ei, int m, int g,
                                          int& s, int& d) {
    if (g < NE) {
        if (m) { s = ei[2 * (size_t)g]; d = ei[2 * ((size_t)NE + g)]; }
        else   { s = ei[g];             d = ei[NE + g]; }
    } else {
        s = d = g - NE;  // self loop
    }
    s = s < 0 ? 0 : (s >= NN ? NN - 1 : s);
    d = d < 0 ? 0 : (d >= NN ? NN - 1 : d);
}

// ---- weight transpose + augmented score rows (device helper) ----
__device__ __forceinline__ void wcvt_att_job(
    const float* __restrict__ W, const float* __restrict__ as,
    const float* __restrict__ ad, int K, int N, int H, u16* __restrict__ Wt,
    int idx) {
    if (idx >= K * (N + 16)) return;
    int n = idx / K, k = idx - n * K;
    if (n < N) { Wt[idx] = f2b(W[(size_t)k * N + n]); return; }
    int j = n - N;
    if (j >= 2 * H) { Wt[idx] = 0; return; }
    const float* att = (j & 1) ? ad : as;
    int h = j >> 1, C = N / H;
    float sum = 0.f;
    for (int c = 0; c < C; ++c)
        sum += W[(size_t)k * N + h * C + c] * att[h * C + c];
    Wt[idx] = f2b(sum);
}

// ---- single-pass partition into fixed-capacity bucket slots ----
__global__ __launch_bounds__(1024) void partition_k(
    const int* __restrict__ ei, int* __restrict__ gcursor,
    unsigned* __restrict__ bbuf,
    const float* __restrict__ W1, const float* __restrict__ as1,
    const float* __restrict__ ad1, u16* __restrict__ w1t,
    const float* __restrict__ W2, const float* __restrict__ as2,
    const float* __restrict__ ad2, u16* __restrict__ w2t,
    const float* __restrict__ Wl, u16* __restrict__ wlt) {
    __shared__ int hist[NBKT], base[NBKT], cur[NBKT];
    __shared__ unsigned stash[EPB];
    __shared__ int smode;
    int t = threadIdx.x, b = blockIdx.x;
    // side jobs: W1 on blocks 0..35, W2 on 36..45, Wl transpose on 46
    if (b < 36) wcvt_att_job(W1, as1, ad1, 256, 128, 2, w1t, b * 1024 + t);
    else if (b < 46) wcvt_att_job(W2, as2, ad2, 128, 64, 1, w2t, (b - 36) * 1024 + t);
    else if (b == 46) {
        int n = t >> 6, k = t & 63;  // wlt[16][64] = Wl^T padded
        wlt[n * 64 + k] = (n < NCLS) ? f2b(Wl[k * NCLS + n]) : (u16)0;
    }
    // local dtype detect (wave 0)
    if (t < 64) {
        int nz = 0;
#pragma unroll
        for (int k = 0; k < 4; ++k)
            if (ei[2 * (t * 4 + k) + 1] != 0) nz = 1;
        unsigned long long bal = __ballot(nz);
        if (t == 0) smode = (bal == 0ULL) ? 1 : 0;  // 1 = int64 layout
    }
    for (int i = t; i < NBKT; i += 1024) hist[i] = 0;
    __syncthreads();
    int m = smode;
    int g0 = b * EPB;
    int gend = min(g0 + EPB, EP);
    for (int g = g0 + t; g < gend; g += 1024) {
        int s, d;
        load_edge(ei, m, g, s, d);
        stash[g - g0] = ((unsigned)s << 16) | (unsigned)d;
        atomicAdd(&hist[d >> 8], 1);
    }
    __syncthreads();
    for (int i = t; i < NBKT; i += 1024) {
        base[i] = hist[i] ? atomicAdd(&gcursor[i], hist[i]) : 0;
        cur[i] = 0;
    }
    __syncthreads();
    int cnt = gend - g0;
    for (int l = t; l < cnt; l += 1024) {
        unsigned p = stash[l];
        int d = p & 0xFFFF;
        int bb = d >> 8;
        int r = base[bb] + atomicAdd(&cur[bb], 1);
        if (r < BCAP)
            bbuf[(size_t)bb * BCAP + r] = ((p >> 16) << 8) | (unsigned)(d & 255);
    }
}

// ---- per-bucket fine CSR (bucket-base scan fused in); 1024 threads/block ----
__global__ __launch_bounds__(1024) void bucket_csr_k(const unsigned* __restrict__ bbuf,
                                                     const int* __restrict__ gcursor,
                                                     int* __restrict__ row_ptr,
                                                     u16* __restrict__ csr_src) {
    __shared__ int bsc[256];
    __shared__ int hist[256], scn[256], cur[256];
    __shared__ int se0, scnt, stot;
    int b = blockIdx.x, t = threadIdx.x;
    int v = 0;
    if (t < 256) {
        v = (t < NBKT) ? min(gcursor[t], BCAP) : 0;
        bsc[t] = v;
        hist[t] = 0;
    }
    __syncthreads();
    for (int off = 1; off < 256; off <<= 1) {
        int x = (t < 256 && t >= off) ? bsc[t - off] : 0;
        __syncthreads();
        if (t < 256) bsc[t] += x;
        __syncthreads();
    }
    if (t == b) { se0 = bsc[t] - v; scnt = v; }
    if (t == NBKT - 1) stot = bsc[t];
    __syncthreads();
    int e0 = se0, cnt = scnt;
    const unsigned* bb = bbuf + (size_t)b * BCAP;
    for (int e = t; e < cnt; e += 1024)
        atomicAdd(&hist[bb[e] & 255], 1);
    __syncthreads();
    int hv = 0;
    if (t < 256) { hv = hist[t]; scn[t] = hv; }
    __syncthreads();
    for (int off = 1; off < 256; off <<= 1) {
        int x = (t < 256 && t >= off) ? scn[t - off] : 0;
        __syncthreads();
        if (t < 256) scn[t] += x;
        __syncthreads();
    }
    if (t < 256) {
        int ex = scn[t] - hv;  // exclusive within bucket
        int n = b * 256 + t;
        if (n < NN) row_ptr[n] = e0 + ex;
        cur[t] = e0 + ex;
    }
    __syncthreads();
    for (int e = t; e < cnt; e += 1024) {
        unsigned p = bb[e];
        int pos = atomicAdd(&cur[p & 255], 1);
        csr_src[pos] = (u16)(p >> 8);
    }
    if (b == 0 && t == 0) row_ptr[NN] = stot;
}

// ---- MFMA GEMM + fused scores; C written SLICE-MAJOR [NF/32][NN][32] ----
template <int K, int NF, int H, bool F32A, bool SLICED_A>
__global__ __launch_bounds__(256) void gemm_mfma_att_k(
    const float* __restrict__ Af, const u16* __restrict__ Ab,
    const u16* __restrict__ Wt, u16* __restrict__ C,
    float* __restrict__ a_s, float* __restrict__ a_d) {
    constexpr int NTF = NF / 16, NT = NTF + 1, KS = K / 32;
    const int wave = threadIdx.x >> 6, lane = threadIdx.x & 63;
    const int quad = lane >> 4, l15 = lane & 15;
    const int m0 = blockIdx.x * 64 + wave * 16;
    int rowA = m0 + l15;
    if (rowA >= NN) rowA = NN - 1;
    const float* afp = F32A ? (Af + (size_t)rowA * K + quad * 8) : nullptr;
    const u16* abp = nullptr;
    if constexpr (!F32A) {
        abp = SLICED_A ? (Ab + (size_t)rowA * 32 + quad * 8)
                       : (Ab + (size_t)rowA * K + quad * 8);
    }
    const u16* bptr = Wt + (size_t)l15 * K + quad * 8;
    f32x4 acc[NT] = {};
#pragma unroll
    for (int ks = 0; ks < KS; ++ks) {
        bf16x8 af;
        if constexpr (F32A) {
            float4 v0 = *(const float4*)(afp + ks * 32);
            float4 v1 = *(const float4*)(afp + ks * 32 + 4);
            af[0] = (short)f2b(v0.x); af[1] = (short)f2b(v0.y);
            af[2] = (short)f2b(v0.z); af[3] = (short)f2b(v0.w);
            af[4] = (short)f2b(v1.x); af[5] = (short)f2b(v1.y);
            af[6] = (short)f2b(v1.z); af[7] = (short)f2b(v1.w);
        } else {
            af = SLICED_A ? *(const bf16x8*)(abp + (size_t)ks * (NN * 32))
                          : *(const bf16x8*)(abp + ks * 32);
        }
        bf16x8 bf[NT];
#pragma unroll
        for (int nt = 0; nt < NT; ++nt)
            bf[nt] = *(const bf16x8*)(bptr + (size_t)nt * 16 * K + ks * 32);
#pragma unroll
        for (int nt = 0; nt < NT; ++nt)
            acc[nt] = __builtin_amdgcn_mfma_f32_16x16x32_bf16(af, bf[nt], acc[nt], 0, 0, 0);
    }
#pragma unroll
    for (int nt = 0; nt < NTF; ++nt) {
#pragma unroll
        for (int reg = 0; reg < 4; ++reg) {
            int row = m0 + quad * 4 + reg;
            int c = nt * 16 + l15;
            if (row < NN)
                C[(size_t)(c >> 5) * (NN * 32) + (size_t)row * 32 + (c & 31)] =
                    f2b(acc[nt][reg]);
        }
    }
    if (l15 < 2 * H) {
        int h = l15 >> 1;
        float* dst = (l15 & 1) ? a_d : a_s;
#pragma unroll
        for (int reg = 0; reg < 4; ++reg) {
            int row = m0 + quad * 4 + reg;
            if (row < NN) dst[row * H + h] = acc[NTF][reg];
        }
    }
}

// ---- per-edge alpha precompute for layer 2: A2[e] = src | bf16(ex)<<16 ----
// 2 nodes per wave (lanes 0-31 / 32-63); also writes 1/denominator per node.
__global__ __launch_bounds__(256) void edge_alpha_k(
    const int* __restrict__ row_ptr, const u16* __restrict__ csr_src,
    const float* __restrict__ a_s, const float* __restrict__ a_d,
    unsigned* __restrict__ A2, float* __restrict__ dninv) {
    int wave = threadIdx.x >> 6;
    int pair = blockIdx.x * 4 + wave;
    if (pair >= NN / 2) return;
    int lane = threadIdx.x & 63, half = lane >> 5, hl = lane & 31;
    int node = pair * 2 + half;
    int r0 = row_ptr[node], r1 = row_ptr[node + 1];
    int cnt = r1 - r0;
    int co = max(cnt, __shfl_xor(cnt, 32));
    int nbat = (co + 31) >> 5;
    float adn = a_d[node];
    float dh = 0.f;
    for (int b = 0; b < nbat; ++b) {
        int idx = r0 + b * 32 + hl;
        bool act = idx < r1;
        int sl = act ? (int)csr_src[idx] : 0;
        float e = a_s[sl] + adn;
        e = e > 0.f ? e : 0.2f * e;
        e = fminf(e, 60.f);
        float ex = act ? __expf(e) : 0.f;
        dh += ex;
        if (act)
            __builtin_nontemporal_store(
                (unsigned)sl | ((unsigned)f2b(ex) << 16), A2 + idx);
    }
#pragma unroll
    for (int off = 1; off < 32; off <<= 1) dh += __shfl_xor(dh, off);
    if (hl == 0) dninv[node] = 1.0f / dh;
}

// ---- slice gather: channel-split passes with XCD-L2 affinity ----
// h stored slice-major [NSL][NN][32ch]; slice working set = 3.2 MB fits a
// 4-MB per-XCD L2. blockIdx%8 = XCD (round-robin dispatch heuristic):
// each XCD serves exactly one slice -> random row reads become L2 hits.
// Streams (csr/A2/out) are non-temporal so they can't evict the hot slice.
// 2 nodes per wave; 8 lanes x 8B per row-slice; 4 edges/half per bpermute
// round. USE_EX: per-edge (src|alpha) precomputed -> 1 line-req/edge.
template <int CH, int NSL, int H, bool USE_EX>
__global__ __launch_bounds__(256) void gat_slice_k(
    const int* __restrict__ row_ptr, const u16* __restrict__ csr_src,
    const unsigned* __restrict__ A2, const float* __restrict__ a_s,
    const float* __restrict__ a_d, const float* __restrict__ dninv,
    const u16* __restrict__ h, const float* __restrict__ bias,
    u16* __restrict__ outg) {
    constexpr int SC = CH / NSL;   // 32 channels (64 B) per slice
    constexpr int SUB = 8 / NSL;   // XCDs per slice
    int xcd = blockIdx.x & 7;
    int slice = xcd / SUB;
    int sub = xcd % SUB;
    int pg = (blockIdx.x >> 3) * SUB + sub;
    int wave = threadIdx.x >> 6;
    int pair = pg * 4 + wave;
    if (pair >= NN / 2) return;  // wave-uniform
    int lane = threadIdx.x & 63;
    int half = lane >> 5, hl = lane & 31, q = hl & 7, gh = hl >> 3;
    int node = pair * 2 + half;
    int r0 = row_ptr[node], r1 = row_ptr[node + 1];
    int cnt = r1 - r0;
    int co = max(cnt, __shfl_xor(cnt, 32));
    int nbat = (co + 31) >> 5;
    const unsigned char* hb8 =
        (const unsigned char*)h + (size_t)slice * (NN * 64);
    const int head = (H == 2) ? (slice >> 1) : 0;
    float adn = 0.f, rdn = 0.f;
    if constexpr (USE_EX) rdn = dninv[node];
    else adn = a_d[node * H + head];
    float dh = 0.f;
    float acc[4] = {0.f, 0.f, 0.f, 0.f};
    const int abase = ((half << 5) | gh) << 2;
    for (int b = 0; b < nbat; ++b) {
        int idx = r0 + b * 32 + hl;
        bool act = idx < r1;
        unsigned pex;
        if constexpr (USE_EX) {
            pex = act ? __builtin_nontemporal_load(A2 + idx) : 0u;
        } else {
            int sl = act ? (int)__builtin_nontemporal_load(csr_src + idx) : 0;
            float e = a_s[sl * H + head] + adn;
            e = e > 0.f ? e : 0.2f * e;
            e = fminf(e, 60.f);
            float ex = act ? __expf(e) : 0.f;
            dh += ex;
            pex = (unsigned)sl | ((unsigned)f2b(ex) << 16);
        }
#pragma unroll
        for (int jr = 0; jr < 2; ++jr) {
            int pr[4];
#pragma unroll
            for (int i = 0; i < 4; ++i)
                pr[i] = __builtin_amdgcn_ds_bpermute(
                    abase + ((jr * 16 + i * 4) << 2), (int)pex);
            unsigned hv0[4], hv1[4];
#pragma unroll
            for (int i = 0; i < 4; ++i) {
                const unsigned* p = (const unsigned*)(
                    hb8 + (((unsigned)((unsigned)pr[i] & 0xFFFFu) << 6) + q * 8));
                hv0[i] = p[0];
                hv1[i] = p[1];
            }
#pragma unroll
            for (int i = 0; i < 4; ++i) {
                float exf = __uint_as_float((unsigned)pr[i] & 0xFFFF0000u);
                unsigned w0 = hv0[i], w1 = hv1[i];
                acc[0] += exf * __uint_as_float(w0 << 16);
                acc[1] += exf * __uint_as_float(w0 & 0xFFFF0000u);
                acc[2] += exf * __uint_as_float(w1 << 16);
                acc[3] += exf * __uint_as_float(w1 & 0xFFFF0000u);
            }
        }
    }
    if constexpr (!USE_EX) {
#pragma unroll
        for (int off = 1; off < 32; off <<= 1) dh += __shfl_xor(dh, off);
        rdn = 1.0f / dh;
    }
#pragma unroll
    for (int v = 0; v < 4; ++v) {
        acc[v] += __shfl_xor(acc[v], 8);
        acc[v] += __shfl_xor(acc[v], 16);
    }
    if (gh == 0) {
        float vv[4];
#pragma unroll
        for (int k = 0; k < 4; ++k) {
            float t = acc[k] * rdn + bias[slice * SC + q * 4 + k];
            vv[k] = t > 0.f ? t : expm1f(t);
        }
        unsigned long long ov =
            (unsigned long long)((unsigned)f2b(vv[0]) | ((unsigned)f2b(vv[1]) << 16)) |
            ((unsigned long long)((unsigned)f2b(vv[2]) | ((unsigned)f2b(vv[3]) << 16)) << 32);
        __builtin_nontemporal_store(
            ov, (unsigned long long*)(outg + (size_t)slice * (NN * 32) +
                                      (size_t)node * 32 + q * 4));
    }
}

// ---- head: out[NN][10] = g2[NN][64] (sliced bf16) @ Wl + bl via MFMA ----
__global__ __launch_bounds__(256) void head_gemm_k(
    const u16* __restrict__ A, const u16* __restrict__ Wt,
    const float* __restrict__ bl, float* __restrict__ out) {
    const int wave = threadIdx.x >> 6, lane = threadIdx.x & 63;
    const int quad = lane >> 4, l15 = lane & 15;
    const int m0 = blockIdx.x * 64 + wave * 16;
    int rowA = m0 + l15;
    if (rowA >= NN) rowA = NN - 1;
    const u16* ab = A + (size_t)rowA * 32 + quad * 8;
    const u16* bp = Wt + (size_t)l15 * 64 + quad * 8;
    f32x4 acc = {};
#pragma unroll
    for (int ks = 0; ks < 2; ++ks) {
        bf16x8 af = *(const bf16x8*)(ab + (size_t)ks * (NN * 32));
        bf16x8 bf = *(const bf16x8*)(bp + ks * 32);
        acc = __builtin_amdgcn_mfma_f32_16x16x32_bf16(af, bf, acc, 0, 0, 0);
    }
    if (l15 < NCLS) {
        float blv = bl[l15];
#pragma unroll
        for (int reg = 0; reg < 4; ++reg) {
            int row = m0 + quad * 4 + reg;
            if (row < NN) out[(size_t)row * NCLS + l15] = acc[reg] + blv;
        }
    }
}

extern "C" void kernel_launch(void* const* d_in, const int* in_sizes, int n_in,
                              void* d_out, int out_size, void* d_ws, size_t ws_size,
                              hipStream_t stream) {
    const float* x   = (const float*)d_in[0];
    const int*   ei  = (const int*)d_in[1];
    const float* W1  = (const float*)d_in[2];
    const float* as1 = (const float*)d_in[3];
    const float* ad1 = (const float*)d_in[4];
    const float* b1  = (const float*)d_in[5];
    const float* W2  = (const float*)d_in[6];
    const float* as2 = (const float*)d_in[7];
    const float* ad2 = (const float*)d_in[8];
    const float* b2  = (const float*)d_in[9];
    const float* Wl  = (const float*)d_in[10];
    const float* bl  = (const float*)d_in[11];
    float* out = (float*)d_out;

    // ---- workspace layout (~30 MB, same footprint as before +2KB wlt) ----
    float* ws = (float*)d_ws;
    size_t o = 0;
    u16* hb  = (u16*)(ws + o); o += (size_t)NN * 64;  // h1 [4][NN][32] / h2 [2][NN][32] + g2
    u16* g2  = hb + (size_t)NN * 64;                  // g2 [2][NN][32] (upper half of hb)
    u16* g1  = (u16*)(ws + o); o += (size_t)NN * 64;  // g1 [4][NN][32]; bbuf overlay; A2 overlay
    unsigned* bbuf = (unsigned*)g1;                   // 9.63 MB <= 12.8 MB (until bucket_csr)
    unsigned* A2 = (unsigned*)g1;                     // 6.6 MB (after gemm2 consumed g1)
    float* dn2inv = (float*)((char*)g1 + (size_t)EP * 4);  // +200 KB, still in g1
    u16* w1t = (u16*)(ws + o); o += 144 * 256 / 2;    // bf16 W1^T+att [144][256]
    u16* w2t = (u16*)(ws + o); o += 80 * 128 / 2;     // bf16 W2^T+att [80][128]
    u16* wlt = (u16*)(ws + o); o += 16 * 64 / 2;      // bf16 Wl^T padded [16][64]
    float* a_s = ws + o;       o += (size_t)NN * 2;
    float* a_d = ws + o;       o += (size_t)NN * 2;
    int* ints = (int*)(ws + o);
    size_t io = 0;
    int* gcursor  = ints + io; io += NBKT;
    int* row_ptr  = ints + io; io += NN + 1;
    u16* csr_src  = (u16*)(ints + io); io += (EP + 1) / 2;

    // ---- CSR build ----
    hipMemsetAsync(gcursor, 0, NBKT * sizeof(int), stream);
    partition_k<<<NPB, 1024, 0, stream>>>(ei, gcursor, bbuf,
                                          W1, as1, ad1, w1t, W2, as2, ad2, w2t,
                                          Wl, wlt);
    bucket_csr_k<<<NBKT, 1024, 0, stream>>>(bbuf, gcursor, row_ptr, csr_src);

    const int gemmBlocks = (NN + 63) / 64;  // 782

    // ---- layer 1: GATConv(256 -> 64, heads=2, concat) + ELU ----
    gemm_mfma_att_k<256, 128, 2, true, false><<<gemmBlocks, 256, 0, stream>>>(
        x, nullptr, w1t, hb, a_s, a_d);
    // 4 slices x 2 XCDs; pairs=25000, 4 pairs/block -> 6250 pair-groups,
    // (b>>3) in [0,3125) x SUB=2 -> grid 25000
    gat_slice_k<128, 4, 2, false><<<25000, 256, 0, stream>>>(
        row_ptr, csr_src, nullptr, a_s, a_d, nullptr, hb, b1, g1);

    // ---- layer 2: GATConv(128 -> 64, heads=1) + ELU ----
    gemm_mfma_att_k<128, 64, 1, false, true><<<gemmBlocks, 256, 0, stream>>>(
        nullptr, g1, w2t, hb, a_s, a_d);
    edge_alpha_k<<<(NN / 2 + 3) / 4, 256, 0, stream>>>(
        row_ptr, csr_src, a_s, a_d, A2, dn2inv);
    // 2 slices x 4 XCDs; (b>>3) in [0,1563) x SUB=4 -> grid 12504
    gat_slice_k<64, 2, 1, true><<<12504, 256, 0, stream>>>(
        row_ptr, csr_src, A2, nullptr, nullptr, dn2inv, hb, b2, g2);

    // ---- fused head: out = elu-output @ Wl + bl ----
    head_gemm_k<<<gemmBlocks, 256, 0, stream>>>(g2, wlt, bl, out);
}

// Round 5
// 305.280 us; speedup vs baseline: 1.1827x; 1.1464x over previous
//
#include <hip/hip_runtime.h>

#define NN 50000
#define NE 1600000
#define EP (NE + NN)   // edges + self loops
#define IN_DIM 256
#define HIDD 64
#define NCLS 10
#define NBKT 196                       // destination buckets: d >> 8
#define EPB 8192                       // edges per partition block
#define NPB ((EP + EPB - 1) / EPB)     // 202 partition blocks
#define BCAP 12288                     // fixed bucket capacity (exp 8418 +- 92)

typedef unsigned short u16;
typedef short bf16x8 __attribute__((ext_vector_type(8)));
typedef float f32x4 __attribute__((ext_vector_type(4)));

__device__ __forceinline__ float b2f(u16 v) { return __uint_as_float(((unsigned)v) << 16); }
__device__ __forceinline__ u16 f2b(float f) {
    unsigned u = __float_as_uint(f);
    unsigned r = (u + 0x7FFFu + ((u >> 16) & 1u)) >> 16;
    return (u16)r;
}

__device__ __forceinline__ void load_edge(const int* __restrict__ ei, int m, int g,
                                          int& s, int& d) {
    if (g < NE) {
        if (m) { s = ei[2 * (size_t)g]; d = ei[2 * ((size_t)NE + g)]; }
        else   { s = ei[g];             d = ei[NE + g]; }
    } else {
        s = d = g - NE;  // self loop
    }
    s = s < 0 ? 0 : (s >= NN ? NN - 1 : s);
    d = d < 0 ? 0 : (d >= NN ? NN - 1 : d);
}

// ---- weight transpose + augmented score rows (device helper) ----
__device__ __forceinline__ void wcvt_att_job(
    const float* __restrict__ W, const float* __restrict__ as,
    const float* __restrict__ ad, int K, int N, int H, u16* __restrict__ Wt,
    int idx) {
    if (idx >= K * (N + 16)) return;
    int n = idx / K, k = idx - n * K;
    if (n < N) { Wt[idx] = f2b(W[(size_t)k * N + n]); return; }
    int j = n - N;
    if (j >= 2 * H) { Wt[idx] = 0; return; }
    const float* att = (j & 1) ? ad : as;
    int h = j >> 1, C = N / H;
    float sum = 0.f;
    for (int c = 0; c < C; ++c)
        sum += W[(size_t)k * N + h * C + c] * att[h * C + c];
    Wt[idx] = f2b(sum);
}

// ---- partition pass: LDS counting-sort per block -> COALESCED bbuf writes ----
// Round-5 change: previous version scattered 6.6M single dwords to random
// bucket slots (64 lines/wave). Now edges are sorted by bucket in LDS first,
// so global writes are contiguous runs (~42 edges/bucket/block). Edges are
// re-read from ei for the sort pass (coalesced, cheap) to stay under 64KB LDS.
__global__ __launch_bounds__(1024) void partition_k(
    const int* __restrict__ ei, int* __restrict__ gcursor,
    unsigned* __restrict__ bbuf,
    const float* __restrict__ W1, const float* __restrict__ as1,
    const float* __restrict__ ad1, u16* __restrict__ w1t,
    const float* __restrict__ W2, const float* __restrict__ as2,
    const float* __restrict__ ad2, u16* __restrict__ w2t,
    const float* __restrict__ Wl, u16* __restrict__ wlt) {
    __shared__ int hist[NBKT], base[NBKT], lbase[NBKT], lcur[NBKT];
    __shared__ int psc[256];
    __shared__ unsigned sst[EPB];
    __shared__ int smode;
    int t = threadIdx.x, b = blockIdx.x;
    // side jobs: W1 on blocks 0..35, W2 on 36..45, Wl transpose on 46
    if (b < 36) wcvt_att_job(W1, as1, ad1, 256, 128, 2, w1t, b * 1024 + t);
    else if (b < 46) wcvt_att_job(W2, as2, ad2, 128, 64, 1, w2t, (b - 36) * 1024 + t);
    else if (b == 46) {
        int n = t >> 6, k = t & 63;  // wlt[16][64] = Wl^T padded
        wlt[n * 64 + k] = (n < NCLS) ? f2b(Wl[k * NCLS + n]) : (u16)0;
    }
    // local dtype detect (wave 0)
    if (t < 64) {
        int nz = 0;
#pragma unroll
        for (int k = 0; k < 4; ++k)
            if (ei[2 * (t * 4 + k) + 1] != 0) nz = 1;
        unsigned long long bal = __ballot(nz);
        if (t == 0) smode = (bal == 0ULL) ? 1 : 0;  // 1 = int64 layout
    }
    for (int i = t; i < NBKT; i += 1024) hist[i] = 0;
    __syncthreads();
    int m = smode;
    int g0 = b * EPB;
    int gend = min(g0 + EPB, EP);
    // pass A: histogram
    for (int g = g0 + t; g < gend; g += 1024) {
        int s, d;
        load_edge(ei, m, g, s, d);
        atomicAdd(&hist[d >> 8], 1);
    }
    __syncthreads();
    // exclusive scan of hist -> lbase; claim global bucket ranges -> base
    int hv = 0;
    if (t < 256) { hv = (t < NBKT) ? hist[t] : 0; psc[t] = hv; }
    __syncthreads();
    for (int off = 1; off < 256; off <<= 1) {
        int x = (t < 256 && t >= off) ? psc[t - off] : 0;
        __syncthreads();
        if (t < 256) psc[t] += x;
        __syncthreads();
    }
    if (t < NBKT) {
        lbase[t] = psc[t] - hv;
        lcur[t] = 0;
        base[t] = hv ? atomicAdd(&gcursor[t], hv) : 0;
    }
    __syncthreads();
    // pass B: re-read edges, scatter into LDS sorted-by-bucket order
    for (int g = g0 + t; g < gend; g += 1024) {
        int s, d;
        load_edge(ei, m, g, s, d);
        unsigned p = ((unsigned)s << 16) | (unsigned)d;
        int bb = d >> 8;
        int r = lbase[bb] + atomicAdd(&lcur[bb], 1);
        sst[r] = p;
    }
    __syncthreads();
    // pass C: coalesced global write (consecutive l in same bucket)
    int cnt = gend - g0;
    for (int l = t; l < cnt; l += 1024) {
        unsigned p = sst[l];
        int bb = (p & 0xFFFF) >> 8;
        int gp = base[bb] + (l - lbase[bb]);
        if (gp < BCAP)  // harden: adversarial skew can't write OOB
            bbuf[(size_t)bb * BCAP + gp] = ((p >> 16) << 8) | (p & 255u);
    }
}

// ---- per-bucket fine CSR; LDS sort -> COALESCED csr_src writes ----
__global__ __launch_bounds__(1024) void bucket_csr_k(const unsigned* __restrict__ bbuf,
                                                     const int* __restrict__ gcursor,
                                                     int* __restrict__ row_ptr,
                                                     u16* __restrict__ csr_src) {
    __shared__ int bsc[256];
    __shared__ int hist[256], scn[256], cur[256];
    __shared__ int se0, scnt, stot;
    __shared__ u16 srt[BCAP];
    int b = blockIdx.x, t = threadIdx.x;
    int v = 0;
    if (t < 256) {
        v = (t < NBKT) ? min(gcursor[t], BCAP) : 0;
        bsc[t] = v;
        hist[t] = 0;
    }
    __syncthreads();
    for (int off = 1; off < 256; off <<= 1) {
        int x = (t < 256 && t >= off) ? bsc[t - off] : 0;
        __syncthreads();
        if (t < 256) bsc[t] += x;
        __syncthreads();
    }
    if (t == b) { se0 = bsc[t] - v; scnt = v; }
    if (t == NBKT - 1) stot = bsc[t];
    __syncthreads();
    int e0 = se0, cnt = scnt;
    const unsigned* bb = bbuf + (size_t)b * BCAP;
    for (int e = t; e < cnt; e += 1024)
        atomicAdd(&hist[bb[e] & 255], 1);
    __syncthreads();
    int hv = 0;
    if (t < 256) { hv = hist[t]; scn[t] = hv; }
    __syncthreads();
    for (int off = 1; off < 256; off <<= 1) {
        int x = (t < 256 && t >= off) ? scn[t - off] : 0;
        __syncthreads();
        if (t < 256) scn[t] += x;
        __syncthreads();
    }
    if (t < 256) {
        int ex = scn[t] - hv;  // exclusive within bucket (LOCAL offset)
        int n = b * 256 + t;
        if (n < NN) row_ptr[n] = e0 + ex;
        cur[t] = ex;
    }
    __syncthreads();
    // sort into LDS by node, then write csr_src coalesced
    for (int e = t; e < cnt; e += 1024) {
        unsigned p = bb[e];
        int pos = atomicAdd(&cur[p & 255], 1);
        srt[pos] = (u16)(p >> 8);
    }
    __syncthreads();
    for (int e = t; e < cnt; e += 1024)
        csr_src[e0 + e] = srt[e];
    if (b == 0 && t == 0) row_ptr[NN] = stot;
}

// ---- MFMA GEMM + fused scores; C row-major or slice-major [NF/32][NN][32] ----
template <int K, int NF, int H, bool F32A, bool SLICED_A, bool SLICED_C>
__global__ __launch_bounds__(256) void gemm_mfma_att_k(
    const float* __restrict__ Af, const u16* __restrict__ Ab,
    const u16* __restrict__ Wt, u16* __restrict__ C,
    float* __restrict__ a_s, float* __restrict__ a_d) {
    constexpr int NTF = NF / 16, NT = NTF + 1, KS = K / 32;
    const int wave = threadIdx.x >> 6, lane = threadIdx.x & 63;
    const int quad = lane >> 4, l15 = lane & 15;
    const int m0 = blockIdx.x * 64 + wave * 16;
    int rowA = m0 + l15;
    if (rowA >= NN) rowA = NN - 1;
    const float* afp = F32A ? (Af + (size_t)rowA * K + quad * 8) : nullptr;
    const u16* abp = nullptr;
    if constexpr (!F32A) {
        abp = SLICED_A ? (Ab + (size_t)rowA * 32 + quad * 8)
                       : (Ab + (size_t)rowA * K + quad * 8);
    }
    const u16* bptr = Wt + (size_t)l15 * K + quad * 8;
    f32x4 acc[NT] = {};
#pragma unroll
    for (int ks = 0; ks < KS; ++ks) {
        bf16x8 af;
        if constexpr (F32A) {
            float4 v0 = *(const float4*)(afp + ks * 32);
            float4 v1 = *(const float4*)(afp + ks * 32 + 4);
            af[0] = (short)f2b(v0.x); af[1] = (short)f2b(v0.y);
            af[2] = (short)f2b(v0.z); af[3] = (short)f2b(v0.w);
            af[4] = (short)f2b(v1.x); af[5] = (short)f2b(v1.y);
            af[6] = (short)f2b(v1.z); af[7] = (short)f2b(v1.w);
        } else {
            af = SLICED_A ? *(const bf16x8*)(abp + (size_t)ks * (NN * 32))
                          : *(const bf16x8*)(abp + ks * 32);
        }
        bf16x8 bf[NT];
#pragma unroll
        for (int nt = 0; nt < NT; ++nt)
            bf[nt] = *(const bf16x8*)(bptr + (size_t)nt * 16 * K + ks * 32);
#pragma unroll
        for (int nt = 0; nt < NT; ++nt)
            acc[nt] = __builtin_amdgcn_mfma_f32_16x16x32_bf16(af, bf[nt], acc[nt], 0, 0, 0);
    }
#pragma unroll
    for (int nt = 0; nt < NTF; ++nt) {
#pragma unroll
        for (int reg = 0; reg < 4; ++reg) {
            int row = m0 + quad * 4 + reg;
            int c = nt * 16 + l15;
            if (row < NN) {
                if constexpr (SLICED_C)
                    C[(size_t)(c >> 5) * (NN * 32) + (size_t)row * 32 + (c & 31)] =
                        f2b(acc[nt][reg]);
                else
                    C[(size_t)row * NF + c] = f2b(acc[nt][reg]);
            }
        }
    }
    if (l15 < 2 * H) {
        int h = l15 >> 1;
        float* dst = (l15 & 1) ? a_d : a_s;
#pragma unroll
        for (int reg = 0; reg < 4; ++reg) {
            int row = m0 + quad * 4 + reg;
            if (row < NN) dst[row * H + h] = acc[NTF][reg];
        }
    }
}

// ---- layer-1 fused gather (round-0 proven structure): one WAVE per node ----
// Full 256B h-row per edge via 64x4B lanes; JB=16 readlane broadcast.
// Only change vs round 0: output store is SLICE-MAJOR [4][NN][32] so the
// layer-2 GEMM can read it with its SLICED_A path.
template <int CH, int H, bool HEAD>
__global__ __launch_bounds__(256) void gat_gather_k(
    const int* __restrict__ row_ptr, const u16* __restrict__ csr_src,
    const float* __restrict__ a_s, const float* __restrict__ a_d,
    const u16* __restrict__ h, const float* __restrict__ bias,
    u16* __restrict__ outg, const float* __restrict__ Wl,
    const float* __restrict__ bl, float* __restrict__ outh) {
    constexpr int VEC = CH / 64;
    constexpr int JB = 16;
    int n = (blockIdx.x * blockDim.x + threadIdx.x) >> 6;  // global wave id = node
    int lane = threadIdx.x & 63;
    if (n >= NN) return;  // wave-uniform exit
    int r0 = row_ptr[n], r1 = row_ptr[n + 1];
    const bool hi = (VEC == 2) ? (lane >= 32) : false;
    const int shl16 = hi ? 0 : 16;  // select my head's bf16 ex into bits 31..16

    float adn0, adn1 = 0.f;
    if (H == 2) {
        float2 adv = *(const float2*)(a_d + n * 2);
        adn0 = adv.x; adn1 = adv.y;
    } else {
        adn0 = a_d[n];
    }

    float dh0 = 0.f, dh1 = 0.f;
    float acc[VEC];
#pragma unroll
    for (int v = 0; v < VEC; ++v) acc[v] = 0.f;

    for (int base = r0; base < r1; base += 64) {
        int cnt = min(64, r1 - base);
        int idx = base + lane;
        bool act = idx < r1;
        int sl = act ? (int)csr_src[idx] : 0;
        unsigned pex;   // H==2: bf16(ex0)|bf16(ex1)<<16 ; H==1: s|bf16(ex)<<16
        if (H == 2) {
            float2 av = *(const float2*)(a_s + sl * 2);
            float e0 = av.x + adn0;
            e0 = e0 > 0.f ? e0 : 0.2f * e0;
            e0 = fminf(e0, 60.f);
            float ex0 = act ? __expf(e0) : 0.f;
            dh0 += ex0;
            float e1 = av.y + adn1;
            e1 = e1 > 0.f ? e1 : 0.2f * e1;
            e1 = fminf(e1, 60.f);
            float ex1 = act ? __expf(e1) : 0.f;
            dh1 += ex1;
            pex = (unsigned)f2b(ex0) | ((unsigned)f2b(ex1) << 16);
        } else {
            float e0 = a_s[sl] + adn0;
            e0 = e0 > 0.f ? e0 : 0.2f * e0;
            e0 = fminf(e0, 60.f);
            float ex0 = act ? __expf(e0) : 0.f;
            dh0 += ex0;
            pex = (unsigned)sl | ((unsigned)f2b(ex0) << 16);
        }
        for (int j0 = 0; j0 < cnt; j0 += JB) {
            if (VEC == 2) {
                int ssu[JB];
                unsigned peu[JB];
#pragma unroll
                for (int i = 0; i < JB; ++i) {
                    ssu[i] = __builtin_amdgcn_readlane(sl, j0 + i);
                    peu[i] = (unsigned)__builtin_amdgcn_readlane((int)pex, j0 + i);
                }
                unsigned hv[JB];
#pragma unroll
                for (int i = 0; i < JB; ++i)
                    hv[i] = ((const unsigned*)(h + (size_t)ssu[i] * CH))[lane];
#pragma unroll
                for (int i = 0; i < JB; ++i) {
                    float exv = __uint_as_float((peu[i] << shl16) & 0xFFFF0000u);
                    acc[0] += exv * __uint_as_float(hv[i] << 16);
                    acc[1] += exv * __uint_as_float(hv[i] & 0xFFFF0000u);
                }
            } else {
                unsigned peu[JB];
#pragma unroll
                for (int i = 0; i < JB; ++i)
                    peu[i] = (unsigned)__builtin_amdgcn_readlane((int)pex, j0 + i);
                u16 hv[JB];
#pragma unroll
                for (int i = 0; i < JB; ++i)
                    hv[i] = (h + (size_t)(peu[i] & 0xFFFFu) * CH)[lane];
#pragma unroll
                for (int i = 0; i < JB; ++i)
                    acc[0] += __uint_as_float(peu[i] & 0xFFFF0000u) * b2f(hv[i]);
            }
        }
    }

#pragma unroll
    for (int off = 32; off; off >>= 1) dh0 += __shfl_xor(dh0, off);
    float dn = dh0;
    if (H == 2) {
#pragma unroll
        for (int off = 32; off; off >>= 1) dh1 += __shfl_xor(dh1, off);
        dn = hi ? dh1 : dh0;
    }

    if (VEC == 2) {
        int c = lane * 2;
        float2 bv = *(const float2*)(bias + c);
        float v0 = acc[0] / dn + bv.x;
        float v1 = acc[1] / dn + bv.y;
        v0 = v0 > 0.f ? v0 : expm1f(v0);
        v1 = v1 > 0.f ? v1 : expm1f(v1);
        ushort2 ov;
        ov.x = f2b(v0); ov.y = f2b(v1);
        // slice-major store: slice = c>>5, offset within = c&31
        *(ushort2*)(outg + (size_t)(c >> 5) * (NN * 32) + (size_t)n * 32 + (c & 31)) = ov;
    } else {
        float v0 = acc[0] / dn + bias[lane];
        v0 = v0 > 0.f ? v0 : expm1f(v0);
        if (HEAD) {
#pragma unroll
            for (int cls = 0; cls < NCLS; ++cls) {
                float p = v0 * Wl[lane * NCLS + cls];
#pragma unroll
                for (int off = 32; off; off >>= 1) p += __shfl_xor(p, off);
                if (lane == cls) outh[(size_t)n * NCLS + cls] = p + bl[cls];
            }
        } else {
            outg[(size_t)n * CH + lane] = f2b(v0);
        }
    }
}

// ---- per-edge alpha precompute for layer 2: A2[e] = src | bf16(ex)<<16 ----
__global__ __launch_bounds__(256) void edge_alpha_k(
    const int* __restrict__ row_ptr, const u16* __restrict__ csr_src,
    const float* __restrict__ a_s, const float* __restrict__ a_d,
    unsigned* __restrict__ A2, float* __restrict__ dninv) {
    int wave = threadIdx.x >> 6;
    int pair = blockIdx.x * 4 + wave;
    if (pair >= NN / 2) return;
    int lane = threadIdx.x & 63, half = lane >> 5, hl = lane & 31;
    int node = pair * 2 + half;
    int r0 = row_ptr[node], r1 = row_ptr[node + 1];
    int cnt = r1 - r0;
    int co = max(cnt, __shfl_xor(cnt, 32));
    int nbat = (co + 31) >> 5;
    float adn = a_d[node];
    float dh = 0.f;
    for (int b = 0; b < nbat; ++b) {
        int idx = r0 + b * 32 + hl;
        bool act = idx < r1;
        int sl = act ? (int)csr_src[idx] : 0;
        float e = a_s[sl] + adn;
        e = e > 0.f ? e : 0.2f * e;
        e = fminf(e, 60.f);
        float ex = act ? __expf(e) : 0.f;
        dh += ex;
        if (act)
            __builtin_nontemporal_store(
                (unsigned)sl | ((unsigned)f2b(ex) << 16), A2 + idx);
    }
#pragma unroll
    for (int off = 1; off < 32; off <<= 1) dh += __shfl_xor(dh, off);
    if (hl == 0) dninv[node] = 1.0f / dh;
}

// ---- layer-2 slice gather with XCD-L2 affinity (round-4, USE_EX) ----
template <int CH, int NSL, int H, bool USE_EX>
__global__ __launch_bounds__(256) void gat_slice_k(
    const int* __restrict__ row_ptr, const u16* __restrict__ csr_src,
    const unsigned* __restrict__ A2, const float* __restrict__ a_s,
    const float* __restrict__ a_d, const float* __restrict__ dninv,
    const u16* __restrict__ h, const float* __restrict__ bias,
    u16* __restrict__ outg) {
    constexpr int SC = CH / NSL;   // 32 channels (64 B) per slice
    constexpr int SUB = 8 / NSL;   // XCDs per slice
    int xcd = blockIdx.x & 7;
    int slice = xcd / SUB;
    int sub = xcd % SUB;
    int pg = (blockIdx.x >> 3) * SUB + sub;
    int wave = threadIdx.x >> 6;
    int pair = pg * 4 + wave;
    if (pair >= NN / 2) return;  // wave-uniform
    int lane = threadIdx.x & 63;
    int half = lane >> 5, hl = lane & 31, q = hl & 7, gh = hl >> 3;
    int node = pair * 2 + half;
    int r0 = row_ptr[node], r1 = row_ptr[node + 1];
    int cnt = r1 - r0;
    int co = max(cnt, __shfl_xor(cnt, 32));
    int nbat = (co + 31) >> 5;
    const unsigned char* hb8 =
        (const unsigned char*)h + (size_t)slice * (NN * 64);
    const int head = (H == 2) ? (slice >> 1) : 0;
    float adn = 0.f, rdn = 0.f;
    if constexpr (USE_EX) rdn = dninv[node];
    else adn = a_d[node * H + head];
    float dh = 0.f;
    float acc[4] = {0.f, 0.f, 0.f, 0.f};
    const int abase = ((half << 5) | gh) << 2;
    for (int b = 0; b < nbat; ++b) {
        int idx = r0 + b * 32 + hl;
        bool act = idx < r1;
        unsigned pex;
        if constexpr (USE_EX) {
            pex = act ? __builtin_nontemporal_load(A2 + idx) : 0u;
        } else {
            int sl = act ? (int)__builtin_nontemporal_load(csr_src + idx) : 0;
            float e = a_s[sl * H + head] + adn;
            e = e > 0.f ? e : 0.2f * e;
            e = fminf(e, 60.f);
            float ex = act ? __expf(e) : 0.f;
            dh += ex;
            pex = (unsigned)sl | ((unsigned)f2b(ex) << 16);
        }
#pragma unroll
        for (int jr = 0; jr < 2; ++jr) {
            int pr[4];
#pragma unroll
            for (int i = 0; i < 4; ++i)
                pr[i] = __builtin_amdgcn_ds_bpermute(
                    abase + ((jr * 16 + i * 4) << 2), (int)pex);
            unsigned hv0[4], hv1[4];
#pragma unroll
            for (int i = 0; i < 4; ++i) {
                const unsigned* p = (const unsigned*)(
                    hb8 + (((unsigned)((unsigned)pr[i] & 0xFFFFu) << 6) + q * 8));
                hv0[i] = p[0];
                hv1[i] = p[1];
            }
#pragma unroll
            for (int i = 0; i < 4; ++i) {
                float exf = __uint_as_float((unsigned)pr[i] & 0xFFFF0000u);
                unsigned w0 = hv0[i], w1 = hv1[i];
                acc[0] += exf * __uint_as_float(w0 << 16);
                acc[1] += exf * __uint_as_float(w0 & 0xFFFF0000u);
                acc[2] += exf * __uint_as_float(w1 << 16);
                acc[3] += exf * __uint_as_float(w1 & 0xFFFF0000u);
            }
        }
    }
    if constexpr (!USE_EX) {
#pragma unroll
        for (int off = 1; off < 32; off <<= 1) dh += __shfl_xor(dh, off);
        rdn = 1.0f / dh;
    }
#pragma unroll
    for (int v = 0; v < 4; ++v) {
        acc[v] += __shfl_xor(acc[v], 8);
        acc[v] += __shfl_xor(acc[v], 16);
    }
    if (gh == 0) {
        float vv[4];
#pragma unroll
        for (int k = 0; k < 4; ++k) {
            float t = acc[k] * rdn + bias[slice * SC + q * 4 + k];
            vv[k] = t > 0.f ? t : expm1f(t);
        }
        unsigned long long ov =
            (unsigned long long)((unsigned)f2b(vv[0]) | ((unsigned)f2b(vv[1]) << 16)) |
            ((unsigned long long)((unsigned)f2b(vv[2]) | ((unsigned)f2b(vv[3]) << 16)) << 32);
        __builtin_nontemporal_store(
            ov, (unsigned long long*)(outg + (size_t)slice * (NN * 32) +
                                      (size_t)node * 32 + q * 4));
    }
}

// ---- head: out[NN][10] = g2[NN][64] (sliced bf16) @ Wl + bl via MFMA ----
__global__ __launch_bounds__(256) void head_gemm_k(
    const u16* __restrict__ A, const u16* __restrict__ Wt,
    const float* __restrict__ bl, float* __restrict__ out) {
    const int wave = threadIdx.x >> 6, lane = threadIdx.x & 63;
    const int quad = lane >> 4, l15 = lane & 15;
    const int m0 = blockIdx.x * 64 + wave * 16;
    int rowA = m0 + l15;
    if (rowA >= NN) rowA = NN - 1;
    const u16* ab = A + (size_t)rowA * 32 + quad * 8;
    const u16* bp = Wt + (size_t)l15 * 64 + quad * 8;
    f32x4 acc = {};
#pragma unroll
    for (int ks = 0; ks < 2; ++ks) {
        bf16x8 af = *(const bf16x8*)(ab + (size_t)ks * (NN * 32));
        bf16x8 bf = *(const bf16x8*)(bp + ks * 32);
        acc = __builtin_amdgcn_mfma_f32_16x16x32_bf16(af, bf, acc, 0, 0, 0);
    }
    if (l15 < NCLS) {
        float blv = bl[l15];
#pragma unroll
        for (int reg = 0; reg < 4; ++reg) {
            int row = m0 + quad * 4 + reg;
            if (row < NN) out[(size_t)row * NCLS + l15] = acc[reg] + blv;
        }
    }
}

extern "C" void kernel_launch(void* const* d_in, const int* in_sizes, int n_in,
                              void* d_out, int out_size, void* d_ws, size_t ws_size,
                              hipStream_t stream) {
    const float* x   = (const float*)d_in[0];
    const int*   ei  = (const int*)d_in[1];
    const float* W1  = (const float*)d_in[2];
    const float* as1 = (const float*)d_in[3];
    const float* ad1 = (const float*)d_in[4];
    const float* b1  = (const float*)d_in[5];
    const float* W2  = (const float*)d_in[6];
    const float* as2 = (const float*)d_in[7];
    const float* ad2 = (const float*)d_in[8];
    const float* b2  = (const float*)d_in[9];
    const float* Wl  = (const float*)d_in[10];
    const float* bl  = (const float*)d_in[11];
    float* out = (float*)d_out;

    // ---- workspace layout (~30 MB) ----
    float* ws = (float*)d_ws;
    size_t o = 0;
    u16* hb  = (u16*)(ws + o); o += (size_t)NN * 64;  // h1 [NN][128] row-major / h2 [2][NN][32] + g2
    u16* g2  = hb + (size_t)NN * 64;                  // g2 [2][NN][32] (upper half of hb)
    u16* g1  = (u16*)(ws + o); o += (size_t)NN * 64;  // g1 [4][NN][32]; bbuf overlay; A2 overlay
    unsigned* bbuf = (unsigned*)g1;                   // 9.63 MB <= 12.8 MB (until bucket_csr)
    unsigned* A2 = (unsigned*)g1;                     // 6.6 MB (after gemm2 consumed g1)
    float* dn2inv = (float*)((char*)g1 + (size_t)EP * 4);  // +200 KB, still in g1
    u16* w1t = (u16*)(ws + o); o += 144 * 256 / 2;    // bf16 W1^T+att [144][256]
    u16* w2t = (u16*)(ws + o); o += 80 * 128 / 2;     // bf16 W2^T+att [80][128]
    u16* wlt = (u16*)(ws + o); o += 16 * 64 / 2;      // bf16 Wl^T padded [16][64]
    float* a_s = ws + o;       o += (size_t)NN * 2;
    float* a_d = ws + o;       o += (size_t)NN * 2;
    int* ints = (int*)(ws + o);
    size_t io = 0;
    int* gcursor  = ints + io; io += NBKT;
    int* row_ptr  = ints + io; io += NN + 1;
    u16* csr_src  = (u16*)(ints + io); io += (EP + 1) / 2;

    // ---- CSR build ----
    hipMemsetAsync(gcursor, 0, NBKT * sizeof(int), stream);
    partition_k<<<NPB, 1024, 0, stream>>>(ei, gcursor, bbuf,
                                          W1, as1, ad1, w1t, W2, as2, ad2, w2t,
                                          Wl, wlt);
    bucket_csr_k<<<NBKT, 1024, 0, stream>>>(bbuf, gcursor, row_ptr, csr_src);

    const int gemmBlocks = (NN + 63) / 64;  // 782
    const int gatherBlocks = (NN + 3) / 4;  // 4 waves (nodes) per 256-thread block

    // ---- layer 1: GATConv(256 -> 64, heads=2, concat) + ELU ----
    gemm_mfma_att_k<256, 128, 2, true, false, false><<<gemmBlocks, 256, 0, stream>>>(
        x, nullptr, w1t, hb, a_s, a_d);
    gat_gather_k<128, 2, false><<<gatherBlocks, 256, 0, stream>>>(
        row_ptr, csr_src, a_s, a_d, hb, b1, g1, nullptr, nullptr, nullptr);

    // ---- layer 2: GATConv(128 -> 64, heads=1) + ELU ----
    gemm_mfma_att_k<128, 64, 1, false, true, true><<<gemmBlocks, 256, 0, stream>>>(
        nullptr, g1, w2t, hb, a_s, a_d);
    edge_alpha_k<<<(NN / 2 + 3) / 4, 256, 0, stream>>>(
        row_ptr, csr_src, a_s, a_d, A2, dn2inv);
    // 2 slices x 4 XCDs; (b>>3) in [0,1563) x SUB=4 -> grid 12504
    gat_slice_k<64, 2, 1, true><<<12504, 256, 0, stream>>>(
        row_ptr, csr_src, A2, nullptr, nullptr, dn2inv, hb, b2, g2);

    // ---- fused head: out = elu-output @ Wl + bl ----
    head_gemm_k<<<gemmBlocks, 256, 0, stream>>>(g2, wlt, bl, out);
}